// Round 3
// baseline (1210.628 us; speedup 1.0000x reference)
//
#include <hip/hip_runtime.h>
#include <cmath>

typedef __bf16 bf16;
typedef __bf16 bf16x4_t __attribute__((ext_vector_type(4)));
typedef __bf16 bf16x8_t __attribute__((ext_vector_type(8)));
typedef float f32x4 __attribute__((ext_vector_type(4)));

#define GAS __attribute__((address_space(1)))
#define LAS __attribute__((address_space(3)))

// ---------------------------------------------------------------------------
// BFP quant-dequant (group=16 along K, m_bit=8) fp32 -> bf16 (values exact).
// Near-roofline (~70 us for 432 MiB) -- unchanged.
// ---------------------------------------------------------------------------
__global__ __launch_bounds__(256) void bfp_quant_f32_to_bf16(
    const float* __restrict__ x, bf16* __restrict__ y, long long n4) {
  long long t = (long long)blockIdx.x * 256 + threadIdx.x;
  if (t >= n4) return;
  const float4 v = reinterpret_cast<const float4*>(x)[t];

  float a = fmaxf(fmaxf(fabsf(v.x), fabsf(v.y)), fmaxf(fabsf(v.z), fabsf(v.w)));
  a = fmaxf(a, __shfl_xor(a, 1));
  a = fmaxf(a, __shfl_xor(a, 2));   // group max over 4 lanes = 16 elems

  float q0, q1, q2, q3;
  if (a > 0.0f) {
    int ex = (int)((__float_as_uint(a) >> 23) & 0xffu) - 127;
    float scale = ldexpf(1.0f, ex - 7);   // 2^(ex-7)
    float inv   = ldexpf(1.0f, 7 - ex);   // exact power of 2: x*inv == x/scale
    q0 = fminf(fmaxf(rintf(v.x * inv), -127.0f), 127.0f) * scale;
    q1 = fminf(fmaxf(rintf(v.y * inv), -127.0f), 127.0f) * scale;
    q2 = fminf(fmaxf(rintf(v.z * inv), -127.0f), 127.0f) * scale;
    q3 = fminf(fmaxf(rintf(v.w * inv), -127.0f), 127.0f) * scale;
  } else {
    q0 = q1 = q2 = q3 = 0.0f;
  }
  bf16x4_t o = { (__bf16)q0, (__bf16)q1, (__bf16)q2, (__bf16)q3 };
  reinterpret_cast<bf16x4_t*>(y)[t] = o;
}

// ---------------------------------------------------------------------------
// GEMM: C[M,N] = A[M,K] * B[N,K]^T + bias[N], bf16 in / fp32 out.
// 256x256 tile, BK=64, 512 threads (8 waves 2Mx4N), 128 KiB dbuf LDS,
// st_16x32 swizzle (bank-conflict-free, verified 0 in round 1).
//
// Register-level software pipeline, one phase ahead. Every ds_read is
// issued one phase before consumption, so its latency hides under the
// previous phase's MFMA region + barriers:
//   p1 window: prefetch a1 (p2/p3)          | stage B(t+1).h0
//   p2 window: prefetch b1 (p3/p4)          | stage B(t+1).h1
//   p3 window: --                           | stage A(t+2).h0 -> Asc
//   p4 window: prefetch NEXT a0/b0 (t+1.p1) | stage A(t+2).h1 -> Asc
// Steady state has ZERO reads on the serial path (old: 24/K-tile).
//
// Waits (one lgkm drain + one counted vmcnt per K-tile):
//   END_BAR(p2): s_waitcnt lgkmcnt(0) -- full drain: every read of regions
//     overwritten at p3/p4/next-p1 is complete >=1 barrier beforehand.
//   END_BAR(p3): s_waitcnt vmcnt(2)   -- tile t+1 fully landed (drains
//     A(t+1) 4 + B(t+1) 4, keeps A(t+2).h0 2 in flight), so p4's
//     read-ahead of buf(t+1) is safe. Never vmcnt(0) in the loop.
// K-loop unrolled x2 (NT even) for register/buffer rotation, zero selects.
// ---------------------------------------------------------------------------
#define BM 256
#define BN 256
#define BK 64
#define THREADS 512

#define BAR() do {                                          \
    asm volatile("" ::: "memory");                          \
    __builtin_amdgcn_s_barrier();                           \
    asm volatile("" ::: "memory");                          \
  } while (0)

template <int H>
__device__ __forceinline__ void stage_half(const char* gb, char* ldsb,
                                           const int goff[4], long long kb,
                                           int tid) {
#pragma unroll
  for (int i = 2 * H; i < 2 * H + 2; ++i) {
    __builtin_amdgcn_global_load_lds(
        (const GAS unsigned int*)(gb + (goff[i] + kb)),
        (LAS unsigned int*)(ldsb + tid * 16 + i * 8192), 16, 0, 0);
  }
}

// One K-tile (4 phases). a0/b0: this tile's operands (already in regs).
// a0n/b0n: filled with NEXT tile's operands during p4. Asc also receives
// A(t+2) staging (its data is dead after the p1 reads + p2 drain).
__device__ __forceinline__ void ktile(
    char* const Asc, char* const Bsc, char* const Bsn, char* const AsN,
    bf16x8_t (&a0)[4][2], bf16x8_t (&b0)[2][2],
    bf16x8_t (&a0n)[4][2], bf16x8_t (&b0n)[2][2],
    f32x4 (&acc)[8][4],
    const char* Ab, const char* Bb, const int* goff,
    long long kbB, long long kbA, int tid, int wofs, int wr, int wc) {
  bf16x8_t a1[4][2], b1[2][2];

  // ---- p1 window: prefetch a1; stage B(t+1).h0 ---- MFMA Q00
#pragma unroll
  for (int m = 0; m < 4; ++m)
#pragma unroll
    for (int ks = 0; ks < 2; ++ks)
      a1[m][ks] = *(const bf16x8_t*)(Asc + ((((wr * 8 + 4 + m) * 2 + ks) << 10) + wofs));
  stage_half<0>(Bb, Bsn, goff, kbB, tid);
  BAR();
  __builtin_amdgcn_s_setprio(1);
#pragma unroll
  for (int m = 0; m < 4; ++m)
#pragma unroll
    for (int n = 0; n < 2; ++n)
#pragma unroll
      for (int ks = 0; ks < 2; ++ks)
        acc[m][n] = __builtin_amdgcn_mfma_f32_16x16x32_bf16(
            a0[m][ks], b0[n][ks], acc[m][n], 0, 0, 0);
  __builtin_amdgcn_s_setprio(0);
  BAR();

  // ---- p2 window: prefetch b1; stage B(t+1).h1 ---- MFMA Q10
#pragma unroll
  for (int n = 0; n < 2; ++n)
#pragma unroll
    for (int ks = 0; ks < 2; ++ks)
      b1[n][ks] = *(const bf16x8_t*)(Bsc + ((((wc * 4 + 2 + n) * 2 + ks) << 10) + wofs));
  stage_half<1>(Bb, Bsn, goff, kbB, tid);
  BAR();
  __builtin_amdgcn_s_setprio(1);
#pragma unroll
  for (int m = 0; m < 4; ++m)
#pragma unroll
    for (int n = 0; n < 2; ++n)
#pragma unroll
      for (int ks = 0; ks < 2; ++ks)
        acc[4 + m][n] = __builtin_amdgcn_mfma_f32_16x16x32_bf16(
            a1[m][ks], b0[n][ks], acc[4 + m][n], 0, 0, 0);
  __builtin_amdgcn_s_setprio(0);
  // Full LDS drain: all reads of regions overwritten from p3 onward
  // (A h0/h1 by p3/p4 staging, B(t-1) buf by next-p1 staging) are done.
  asm volatile("s_waitcnt lgkmcnt(0)" ::: "memory");
  BAR();

  // ---- p3 window: stage A(t+2).h0 into Asc ---- MFMA Q11
  stage_half<0>(Ab, Asc, goff, kbA, tid);
  BAR();
  __builtin_amdgcn_s_setprio(1);
#pragma unroll
  for (int m = 0; m < 4; ++m)
#pragma unroll
    for (int n = 0; n < 2; ++n)
#pragma unroll
      for (int ks = 0; ks < 2; ++ks)
        acc[4 + m][2 + n] = __builtin_amdgcn_mfma_f32_16x16x32_bf16(
            a1[m][ks], b1[n][ks], acc[4 + m][2 + n], 0, 0, 0);
  __builtin_amdgcn_s_setprio(0);
  // Counted: drains A(t+1)+B(t+1) (8 oldest), keeps A(t+2).h0 in flight.
  asm volatile("s_waitcnt vmcnt(2)" ::: "memory");
  BAR();

  // ---- p4 window: read-ahead NEXT tile's a0/b0 from buf(t+1);
  //                 stage A(t+2).h1 ---- MFMA Q01
#pragma unroll
  for (int m = 0; m < 4; ++m)
#pragma unroll
    for (int ks = 0; ks < 2; ++ks)
      a0n[m][ks] = *(const bf16x8_t*)(AsN + ((((wr * 8 + m) * 2 + ks) << 10) + wofs));
#pragma unroll
  for (int n = 0; n < 2; ++n)
#pragma unroll
    for (int ks = 0; ks < 2; ++ks)
      b0n[n][ks] = *(const bf16x8_t*)(Bsn + ((((wc * 4 + n) * 2 + ks) << 10) + wofs));
  stage_half<1>(Ab, Asc, goff, kbA, tid);
  BAR();
  __builtin_amdgcn_s_setprio(1);
#pragma unroll
  for (int m = 0; m < 4; ++m)
#pragma unroll
    for (int n = 0; n < 2; ++n)
#pragma unroll
      for (int ks = 0; ks < 2; ++ks)
        acc[m][2 + n] = __builtin_amdgcn_mfma_f32_16x16x32_bf16(
            a0[m][ks], b1[n][ks], acc[m][2 + n], 0, 0, 0);
  __builtin_amdgcn_s_setprio(0);
  BAR();
}

__global__ __launch_bounds__(THREADS, 2) void gemm_bf16_bt_8ph(
    const bf16* __restrict__ A,   // [Mc,K] row-major (chunk)
    const bf16* __restrict__ B,   // [N,K] row-major (i.e. B^T of the GEMM)
    const float* __restrict__ bias,
    float* __restrict__ C,        // [Mc,N] row-major (chunk)
    int N, int K) {
  extern __shared__ char smem[];  // 131072 B: [buf][A 32K | B 32K]

  const int tid  = threadIdx.x;
  const int wave = tid >> 6;
  const int lane = tid & 63;
  const int wr   = wave >> 2;     // 0..1 -> 128 rows of C
  const int wc   = wave & 3;      // 0..3 -> 64 cols of C
  const int quad = lane >> 4;     // 0..3
  const int ln   = lane & 15;
  const int NT   = K / BK;        // must be even (K=4096 -> 64)

  // T1: bijective XCD swizzle (nwg = 16 * (rows/256), always % 8 == 0).
  const int gx   = gridDim.x;
  const int nwg  = gx * gridDim.y;
  const int orig = blockIdx.y * gx + blockIdx.x;
  const int swz  = (orig & 7) * (nwg >> 3) + (orig >> 3);
  const int bm   = swz / gx;
  const int bn   = swz % gx;

  const long long kstride = (long long)K * 2;
  const char* Ab = (const char*)A + (long long)bm * BM * kstride;
  const char* Bb = (const char*)B + (long long)bn * BN * kstride;

  // Per-lane staging source offsets (inverse-swizzled global source so the
  // linear global_load_lds dest + swizzled ds_read form the identity).
  int goff[4];
#pragma unroll
  for (int i = 0; i < 4; ++i) {
    const int o = tid * 16 + i * 8192;
    const int s = o >> 10;          // subtile 0..31
    int w = o & 1023;
    w ^= ((w >> 9) & 1) << 5;       // st_16x32 swizzle
    const int grow = (s >> 1) * 16 + (w >> 6);
    const int gcb  = (s & 1) * 64 + (w & 63);
    goff[i] = grow * (K * 2) + gcb;
  }
  // Swizzled within-subtile ds_read offset.
  const int wofs = (ln * 64 + quad * 16) ^ ((ln & 8) << 2);

  char* const As0 = smem;
  char* const Bs0 = smem + 32768;
  char* const As1 = smem + 65536;
  char* const Bs1 = smem + 98304;

  f32x4 acc[8][4];
#pragma unroll
  for (int m = 0; m < 8; ++m)
#pragma unroll
    for (int n = 0; n < 4; ++n)
      acc[m][n] = (f32x4){0.0f, 0.0f, 0.0f, 0.0f};

  // Prologue: tile 0 into buf0; A(1) into buf1; then pre-read tile0 a0/b0
  // (steady-state entry: A(t+1)'s 4 loads in flight at p1).
  stage_half<0>(Ab, As0, goff, 0, tid);
  stage_half<1>(Ab, As0, goff, 0, tid);
  stage_half<0>(Bb, Bs0, goff, 0, tid);
  stage_half<1>(Bb, Bs0, goff, 0, tid);
  {
    const long long k1 = (NT > 1) ? (long long)BK * 2 : 0;
    stage_half<0>(Ab, As1, goff, k1, tid);
    stage_half<1>(Ab, As1, goff, k1, tid);
  }
  asm volatile("s_waitcnt vmcnt(4)" ::: "memory");  // tile 0 landed
  __builtin_amdgcn_s_barrier();
  asm volatile("" ::: "memory");

  bf16x8_t a0e[4][2], b0e[2][2], a0o[4][2], b0o[2][2];
#pragma unroll
  for (int m = 0; m < 4; ++m)
#pragma unroll
    for (int ks = 0; ks < 2; ++ks)
      a0e[m][ks] = *(const bf16x8_t*)(As0 + ((((wr * 8 + m) * 2 + ks) << 10) + wofs));
#pragma unroll
  for (int n = 0; n < 2; ++n)
#pragma unroll
    for (int ks = 0; ks < 2; ++ks)
      b0e[n][ks] = *(const bf16x8_t*)(Bs0 + ((((wc * 4 + n) * 2 + ks) << 10) + wofs));

  for (int t = 0; t < NT; t += 2) {
    const long long kbB0 = (long long)((t + 1 < NT) ? t + 1 : NT - 1) * (BK * 2);
    const long long kbA0 = (long long)((t + 2 < NT) ? t + 2 : NT - 1) * (BK * 2);
    const long long kbB1 = kbA0;
    const long long kbA1 = (long long)((t + 3 < NT) ? t + 3 : NT - 1) * (BK * 2);
    // even tile t: bufs (As0,Bs0); B(t+1)->Bs1; read-ahead from (As1,Bs1)
    ktile(As0, Bs0, Bs1, As1, a0e, b0e, a0o, b0o, acc,
          Ab, Bb, goff, kbB0, kbA0, tid, wofs, wr, wc);
    // odd tile t+1: bufs (As1,Bs1); B(t+2)->Bs0; read-ahead from (As0,Bs0)
    ktile(As1, Bs1, Bs0, As0, a0o, b0o, a0e, b0e, acc,
          Ab, Bb, goff, kbB1, kbA1, tid, wofs, wr, wc);
  }
  // Drain clamped tail stages + read-aheads before exit.
  asm volatile("s_waitcnt vmcnt(0) lgkmcnt(0)" ::: "memory");

  // Epilogue: C/D mapping col = lane&15, row = quad*4 + reg (m89-verified).
  const long long row0 = (long long)bm * BM + wr * 128;
  const int col0 = bn * BN + wc * 64;
#pragma unroll
  for (int n = 0; n < 4; ++n) {
    const int col = col0 + n * 16 + ln;
    const float bv = bias[col];
#pragma unroll
    for (int m = 0; m < 8; ++m) {
      const long long row = row0 + m * 16 + quad * 4;
#pragma unroll
      for (int r = 0; r < 4; ++r)
        C[(row + r) * (long long)N + col] = acc[m][n][r] + bv;
    }
  }
}

extern "C" void kernel_launch(void* const* d_in, const int* in_sizes, int n_in,
                              void* d_out, int out_size, void* d_ws, size_t ws_size,
                              hipStream_t stream) {
  const float* inp    = (const float*)d_in[0];  // [B,S,K] fp32
  const float* weight = (const float*)d_in[1];  // [N,K]   fp32
  const float* bias   = (const float*)d_in[2];  // [N]     fp32
  float* out = (float*)d_out;                   // [B,S,N] fp32

  const int N = in_sizes[2];              // 4096
  const int K = in_sizes[1] / N;          // 4096
  const int M = in_sizes[0] / K;          // 16384

  // Workspace layout:
  //   [0, qw_bytes)   : qw [N,K] bf16  (32 MiB)
  //   [qw_bytes, ...) : qx chunk [Mc,K] bf16, Mc multiple of BM (=256)
  const size_t qw_bytes  = (size_t)N * K * sizeof(bf16);
  const size_t row_bytes = (size_t)K * sizeof(bf16);

  long long Mc;
  if (ws_size >= qw_bytes + (size_t)M * row_bytes) {
    Mc = M;  // everything fits: single GEMM over the full problem
  } else if (ws_size >= qw_bytes + (size_t)BM * row_bytes) {
    Mc = (long long)((ws_size - qw_bytes) / row_bytes) / BM * BM;
  } else {
    Mc = BM;  // desperate floor; requires ws_size >= 34 MiB for correctness
  }

  bf16* qw = (bf16*)d_ws;
  bf16* qx = (bf16*)((char*)d_ws + qw_bytes);

  // 128 KiB dynamic LDS opt-in (host-side, graph-capture transparent).
  static bool lds_attr_done = false;
  if (!lds_attr_done) {
    (void)hipFuncSetAttribute((const void*)gemm_bf16_bt_8ph,
                              hipFuncAttributeMaxDynamicSharedMemorySize,
                              131072);
    lds_attr_done = true;
  }

  // Quantize weight once (32 MiB bf16).
  const long long n4w = (long long)N * K / 4;
  hipLaunchKernelGGL(bfp_quant_f32_to_bf16, dim3((unsigned)((n4w + 255) / 256)),
                     dim3(256), 0, stream, weight, qw, n4w);

  // Chunk over M: quantize Mc input rows, GEMM them, repeat. Same stream =>
  // serialized; chunk i+1's quant never overlaps chunk i's GEMM reads.
  for (long long m0 = 0; m0 < M; m0 += Mc) {
    const long long rows = (M - m0 < Mc) ? (M - m0) : Mc;
    const long long n4x  = rows * K / 4;
    hipLaunchKernelGGL(bfp_quant_f32_to_bf16, dim3((unsigned)((n4x + 255) / 256)),
                       dim3(256), 0, stream,
                       inp + m0 * K, qx, n4x);
    hipLaunchKernelGGL(gemm_bf16_bt_8ph,
                       dim3(N / BN, (unsigned)(rows / BM)), dim3(THREADS),
                       131072, stream,
                       qx, qw, bias, out + m0 * N, N, K);
  }
}

// Round 4
// 922.196 us; speedup vs baseline: 1.3128x; 1.3128x over previous
//
#include <hip/hip_runtime.h>
#include <cmath>

typedef __bf16 bf16;
typedef __bf16 bf16x4_t __attribute__((ext_vector_type(4)));
typedef __bf16 bf16x8_t __attribute__((ext_vector_type(8)));
typedef float f32x4 __attribute__((ext_vector_type(4)));

#define GAS __attribute__((address_space(1)))
#define LAS __attribute__((address_space(3)))

// ---------------------------------------------------------------------------
// BFP quant-dequant (group=16 along K, m_bit=8) fp32 -> bf16 (values exact).
// Near-roofline (~70 us for 432 MiB) -- unchanged.
// ---------------------------------------------------------------------------
__global__ __launch_bounds__(256) void bfp_quant_f32_to_bf16(
    const float* __restrict__ x, bf16* __restrict__ y, long long n4) {
  long long t = (long long)blockIdx.x * 256 + threadIdx.x;
  if (t >= n4) return;
  const float4 v = reinterpret_cast<const float4*>(x)[t];

  float a = fmaxf(fmaxf(fabsf(v.x), fabsf(v.y)), fmaxf(fabsf(v.z), fabsf(v.w)));
  a = fmaxf(a, __shfl_xor(a, 1));
  a = fmaxf(a, __shfl_xor(a, 2));   // group max over 4 lanes = 16 elems

  float q0, q1, q2, q3;
  if (a > 0.0f) {
    int ex = (int)((__float_as_uint(a) >> 23) & 0xffu) - 127;
    float scale = ldexpf(1.0f, ex - 7);   // 2^(ex-7)
    float inv   = ldexpf(1.0f, 7 - ex);   // exact power of 2: x*inv == x/scale
    q0 = fminf(fmaxf(rintf(v.x * inv), -127.0f), 127.0f) * scale;
    q1 = fminf(fmaxf(rintf(v.y * inv), -127.0f), 127.0f) * scale;
    q2 = fminf(fmaxf(rintf(v.z * inv), -127.0f), 127.0f) * scale;
    q3 = fminf(fmaxf(rintf(v.w * inv), -127.0f), 127.0f) * scale;
  } else {
    q0 = q1 = q2 = q3 = 0.0f;
  }
  bf16x4_t o = { (__bf16)q0, (__bf16)q1, (__bf16)q2, (__bf16)q3 };
  reinterpret_cast<bf16x4_t*>(y)[t] = o;
}

// ---------------------------------------------------------------------------
// GEMM: C[M,N] = A[M,K] * B[N,K]^T + bias[N], bf16 in / fp32 out.
// 256x256 tile, BK=64, 512 threads (8 waves 2Mx4N), 128 KiB dbuf LDS,
// st_16x32 swizzle (bank-conflict-free, verified 0 in round 1).
//
// ROUND-1 BASE (527us, MfmaUtil 45.7) + m201's three deltas:
//  1. Symmetric 2-ahead staging, depth 3 half-tiles, vmcnt(6):
//       p1: stage B(t+1).h1 -> Bsn   (h0 was issued by t-1.p4)
//       p3: stage A(t+2).h0+h1 -> Asc (A reads done at p2)
//       p4: stage B(t+2).h0 -> Bsc    (B reads done at p3); vmcnt(6)
//     In flight at p4's wait: A(t+2) x4 + B(t+2).h0 x2 = 6 (3 half-tiles,
//     m201's formula). B(t+1) slack 3-4 phases (was 2-3), A(t+1) 4-5.
//  2. No sched_barrier(0) in the phase sync (m141: order-pinning costs;
//     reads are compiler-visible so dataflow lgkmcnt protects ordering).
//  3. lgkmcnt(8) pre-barrier throttle on the 12-read phase (m201 template).
//
// Overwrite-hazard ledger (all verified):
//   p3's A(t+2) writes to Asc: a0 consumed by p1 MFMA (lgkm0@p1),
//     a1 by p2 MFMA (lgkm0@p2); p3 issue window is >=1 barrier later.
//   p4's B(t+2).h0 + next-p1's B(t+2).h1 write to Bsc: b0 consumed by
//     p1/p2 MFMA, b1 read@p2 consumed by p3 MFMA (lgkm0@p3); later windows.
//   Reads of buf(t+1) at t+1.p1/p2/p3 gated by t.p4's vmcnt(6) + barrier.
// ---------------------------------------------------------------------------
#define BM 256
#define BN 256
#define BK 64
#define THREADS 512

#define BAR() do {                                          \
    asm volatile("" ::: "memory");                          \
    __builtin_amdgcn_s_barrier();                           \
    asm volatile("" ::: "memory");                          \
  } while (0)

template <int H>
__device__ __forceinline__ void stage_half(const char* gb, char* ldsb,
                                           const int goff[4], long long kb,
                                           int tid) {
#pragma unroll
  for (int i = 2 * H; i < 2 * H + 2; ++i) {
    __builtin_amdgcn_global_load_lds(
        (const GAS unsigned int*)(gb + (goff[i] + kb)),
        (LAS unsigned int*)(ldsb + tid * 16 + i * 8192), 16, 0, 0);
  }
}

// One K-tile (4 phases, m201 template).
__device__ __forceinline__ void ktile(
    char* const Asc, char* const Bsc, char* const Bsn,
    f32x4 (&acc)[8][4],
    const char* Ab, const char* Bb, const int* goff,
    long long kbB1, long long kbAB2, int tid, int wofs, int wr, int wc) {
  bf16x8_t a0[4][2], a1[4][2], b0[2][2], b1[2][2];

  // ---- p1: read a0(8)+b0(4); stage B(t+1).h1; lgkm throttle ---- Q00
#pragma unroll
  for (int m = 0; m < 4; ++m)
#pragma unroll
    for (int ks = 0; ks < 2; ++ks)
      a0[m][ks] = *(const bf16x8_t*)(Asc + ((((wr * 8 + m) * 2 + ks) << 10) + wofs));
#pragma unroll
  for (int n = 0; n < 2; ++n)
#pragma unroll
    for (int ks = 0; ks < 2; ++ks)
      b0[n][ks] = *(const bf16x8_t*)(Bsc + ((((wc * 4 + n) * 2 + ks) << 10) + wofs));
  stage_half<1>(Bb, Bsn, goff, kbB1, tid);
  asm volatile("s_waitcnt lgkmcnt(8)");
  BAR();
  asm volatile("s_waitcnt lgkmcnt(0)");
  __builtin_amdgcn_s_setprio(1);
#pragma unroll
  for (int m = 0; m < 4; ++m)
#pragma unroll
    for (int n = 0; n < 2; ++n)
#pragma unroll
      for (int ks = 0; ks < 2; ++ks)
        acc[m][n] = __builtin_amdgcn_mfma_f32_16x16x32_bf16(
            a0[m][ks], b0[n][ks], acc[m][n], 0, 0, 0);
  __builtin_amdgcn_s_setprio(0);
  BAR();

  // ---- p2: read a1(8); no stage ---- Q10
#pragma unroll
  for (int m = 0; m < 4; ++m)
#pragma unroll
    for (int ks = 0; ks < 2; ++ks)
      a1[m][ks] = *(const bf16x8_t*)(Asc + ((((wr * 8 + 4 + m) * 2 + ks) << 10) + wofs));
  BAR();
  asm volatile("s_waitcnt lgkmcnt(0)");
  __builtin_amdgcn_s_setprio(1);
#pragma unroll
  for (int m = 0; m < 4; ++m)
#pragma unroll
    for (int n = 0; n < 2; ++n)
#pragma unroll
      for (int ks = 0; ks < 2; ++ks)
        acc[4 + m][n] = __builtin_amdgcn_mfma_f32_16x16x32_bf16(
            a1[m][ks], b0[n][ks], acc[4 + m][n], 0, 0, 0);
  __builtin_amdgcn_s_setprio(0);
  BAR();

  // ---- p3: read b1(4); stage A(t+2).h0+h1 -> Asc ---- Q11
#pragma unroll
  for (int n = 0; n < 2; ++n)
#pragma unroll
    for (int ks = 0; ks < 2; ++ks)
      b1[n][ks] = *(const bf16x8_t*)(Bsc + ((((wc * 4 + 2 + n) * 2 + ks) << 10) + wofs));
  stage_half<0>(Ab, Asc, goff, kbAB2, tid);
  stage_half<1>(Ab, Asc, goff, kbAB2, tid);
  BAR();
  asm volatile("s_waitcnt lgkmcnt(0)");
  __builtin_amdgcn_s_setprio(1);
#pragma unroll
  for (int m = 0; m < 4; ++m)
#pragma unroll
    for (int n = 0; n < 2; ++n)
#pragma unroll
      for (int ks = 0; ks < 2; ++ks)
        acc[4 + m][2 + n] = __builtin_amdgcn_mfma_f32_16x16x32_bf16(
            a1[m][ks], b1[n][ks], acc[4 + m][2 + n], 0, 0, 0);
  __builtin_amdgcn_s_setprio(0);
  BAR();

  // ---- p4: stage B(t+2).h0 -> Bsc; counted vmcnt(6) ---- Q01
  stage_half<0>(Bb, Bsc, goff, kbAB2, tid);
  BAR();
  __builtin_amdgcn_s_setprio(1);
#pragma unroll
  for (int m = 0; m < 4; ++m)
#pragma unroll
    for (int n = 0; n < 2; ++n)
#pragma unroll
      for (int ks = 0; ks < 2; ++ks)
        acc[m][2 + n] = __builtin_amdgcn_mfma_f32_16x16x32_bf16(
            a0[m][ks], b1[n][ks], acc[m][2 + n], 0, 0, 0);
  __builtin_amdgcn_s_setprio(0);
  asm volatile("s_waitcnt vmcnt(6)" ::: "memory");  // tile t+1 landed
  BAR();
}

__global__ __launch_bounds__(THREADS, 2) void gemm_bf16_bt_8ph(
    const bf16* __restrict__ A,   // [Mc,K] row-major (chunk)
    const bf16* __restrict__ B,   // [N,K] row-major (i.e. B^T of the GEMM)
    const float* __restrict__ bias,
    float* __restrict__ C,        // [Mc,N] row-major (chunk)
    int N, int K) {
  extern __shared__ char smem[];  // 131072 B: [buf][A 32K | B 32K]

  const int tid  = threadIdx.x;
  const int wave = tid >> 6;
  const int lane = tid & 63;
  const int wr   = wave >> 2;     // 0..1 -> 128 rows of C
  const int wc   = wave & 3;      // 0..3 -> 64 cols of C
  const int quad = lane >> 4;     // 0..3
  const int ln   = lane & 15;
  const int NT   = K / BK;        // must be even (K=4096 -> 64)

  // T1: bijective XCD swizzle (nwg = 16 * (rows/256), always % 8 == 0).
  const int gx   = gridDim.x;
  const int nwg  = gx * gridDim.y;
  const int orig = blockIdx.y * gx + blockIdx.x;
  const int swz  = (orig & 7) * (nwg >> 3) + (orig >> 3);
  const int bm   = swz / gx;
  const int bn   = swz % gx;

  const long long kstride = (long long)K * 2;
  const char* Ab = (const char*)A + (long long)bm * BM * kstride;
  const char* Bb = (const char*)B + (long long)bn * BN * kstride;

  // Per-lane staging source offsets (inverse-swizzled global source so the
  // linear global_load_lds dest + swizzled ds_read form the identity).
  int goff[4];
#pragma unroll
  for (int i = 0; i < 4; ++i) {
    const int o = tid * 16 + i * 8192;
    const int s = o >> 10;          // subtile 0..31
    int w = o & 1023;
    w ^= ((w >> 9) & 1) << 5;       // st_16x32 swizzle
    const int grow = (s >> 1) * 16 + (w >> 6);
    const int gcb  = (s & 1) * 64 + (w & 63);
    goff[i] = grow * (K * 2) + gcb;
  }
  // Swizzled within-subtile ds_read offset.
  const int wofs = (ln * 64 + quad * 16) ^ ((ln & 8) << 2);

  char* const As0 = smem;
  char* const Bs0 = smem + 32768;
  char* const As1 = smem + 65536;
  char* const Bs1 = smem + 98304;

  f32x4 acc[8][4];
#pragma unroll
  for (int m = 0; m < 8; ++m)
#pragma unroll
    for (int n = 0; n < 4; ++n)
      acc[m][n] = (f32x4){0.0f, 0.0f, 0.0f, 0.0f};

  // Prologue (matches steady-state in-flight ordering):
  //   A(0), B(0) -> buf0; A(1) -> buf1; B(1).h0 -> buf1.   14 loads.
  //   vmcnt(6): tile 0 landed, 3 half-tiles (A(1)+B(1).h0) in flight.
  stage_half<0>(Ab, As0, goff, 0, tid);
  stage_half<1>(Ab, As0, goff, 0, tid);
  stage_half<0>(Bb, Bs0, goff, 0, tid);
  stage_half<1>(Bb, Bs0, goff, 0, tid);
  {
    const long long k1 = (NT > 1) ? (long long)BK * 2 : 0;
    stage_half<0>(Ab, As1, goff, k1, tid);
    stage_half<1>(Ab, As1, goff, k1, tid);
    stage_half<0>(Bb, Bs1, goff, k1, tid);
  }
  asm volatile("s_waitcnt vmcnt(6)" ::: "memory");
  __builtin_amdgcn_s_barrier();
  asm volatile("" ::: "memory");

  for (int t = 0; t < NT; t += 2) {
    const long long kbB1e = (long long)((t + 1 < NT) ? t + 1 : NT - 1) * (BK * 2);
    const long long kbAB2e = (long long)((t + 2 < NT) ? t + 2 : NT - 1) * (BK * 2);
    const long long kbB1o = kbAB2e;
    const long long kbAB2o = (long long)((t + 3 < NT) ? t + 3 : NT - 1) * (BK * 2);
    // even tile t: cur (As0,Bs0); B(t+1).h1 -> Bs1; A/B(t+2) -> As0/Bs0
    ktile(As0, Bs0, Bs1, acc, Ab, Bb, goff, kbB1e, kbAB2e, tid, wofs, wr, wc);
    // odd tile t+1: cur (As1,Bs1); B(t+2).h1 -> Bs0; A/B(t+3) -> As1/Bs1
    ktile(As1, Bs1, Bs0, acc, Ab, Bb, goff, kbB1o, kbAB2o, tid, wofs, wr, wc);
  }
  // Drain clamped tail stages before exit.
  asm volatile("s_waitcnt vmcnt(0) lgkmcnt(0)" ::: "memory");

  // Epilogue: C/D mapping col = lane&15, row = quad*4 + reg (m89-verified).
  const long long row0 = (long long)bm * BM + wr * 128;
  const int col0 = bn * BN + wc * 64;
#pragma unroll
  for (int n = 0; n < 4; ++n) {
    const int col = col0 + n * 16 + ln;
    const float bv = bias[col];
#pragma unroll
    for (int m = 0; m < 8; ++m) {
      const long long row = row0 + m * 16 + quad * 4;
#pragma unroll
      for (int r = 0; r < 4; ++r)
        C[(row + r) * (long long)N + col] = acc[m][n][r] + bv;
    }
  }
}

extern "C" void kernel_launch(void* const* d_in, const int* in_sizes, int n_in,
                              void* d_out, int out_size, void* d_ws, size_t ws_size,
                              hipStream_t stream) {
  const float* inp    = (const float*)d_in[0];  // [B,S,K] fp32
  const float* weight = (const float*)d_in[1];  // [N,K]   fp32
  const float* bias   = (const float*)d_in[2];  // [N]     fp32
  float* out = (float*)d_out;                   // [B,S,N] fp32

  const int N = in_sizes[2];              // 4096
  const int K = in_sizes[1] / N;          // 4096
  const int M = in_sizes[0] / K;          // 16384

  // Workspace layout:
  //   [0, qw_bytes)   : qw [N,K] bf16  (32 MiB)
  //   [qw_bytes, ...) : qx chunk [Mc,K] bf16, Mc multiple of BM (=256)
  const size_t qw_bytes  = (size_t)N * K * sizeof(bf16);
  const size_t row_bytes = (size_t)K * sizeof(bf16);

  long long Mc;
  if (ws_size >= qw_bytes + (size_t)M * row_bytes) {
    Mc = M;  // everything fits: single GEMM over the full problem
  } else if (ws_size >= qw_bytes + (size_t)BM * row_bytes) {
    Mc = (long long)((ws_size - qw_bytes) / row_bytes) / BM * BM;
  } else {
    Mc = BM;  // desperate floor; requires ws_size >= 34 MiB for correctness
  }

  bf16* qw = (bf16*)d_ws;
  bf16* qx = (bf16*)((char*)d_ws + qw_bytes);

  // 128 KiB dynamic LDS opt-in (host-side, graph-capture transparent).
  static bool lds_attr_done = false;
  if (!lds_attr_done) {
    (void)hipFuncSetAttribute((const void*)gemm_bf16_bt_8ph,
                              hipFuncAttributeMaxDynamicSharedMemorySize,
                              131072);
    lds_attr_done = true;
  }

  // Quantize weight once (32 MiB bf16).
  const long long n4w = (long long)N * K / 4;
  hipLaunchKernelGGL(bfp_quant_f32_to_bf16, dim3((unsigned)((n4w + 255) / 256)),
                     dim3(256), 0, stream, weight, qw, n4w);

  // Chunk over M: quantize Mc input rows, GEMM them, repeat. Same stream =>
  // serialized; chunk i+1's quant never overlaps chunk i's GEMM reads.
  for (long long m0 = 0; m0 < M; m0 += Mc) {
    const long long rows = (M - m0 < Mc) ? (M - m0) : Mc;
    const long long n4x  = rows * K / 4;
    hipLaunchKernelGGL(bfp_quant_f32_to_bf16, dim3((unsigned)((n4x + 255) / 256)),
                       dim3(256), 0, stream,
                       inp + m0 * K, qx, n4x);
    hipLaunchKernelGGL(gemm_bf16_bt_8ph,
                       dim3(N / BN, (unsigned)(rows / BM)), dim3(THREADS),
                       131072, stream,
                       qx, qw, bias, out + m0 * N, N, K);
  }
}

// Round 5
// 895.075 us; speedup vs baseline: 1.3525x; 1.0303x over previous
//
#include <hip/hip_runtime.h>
#include <cmath>

typedef __bf16 bf16;
typedef __bf16 bf16x4_t __attribute__((ext_vector_type(4)));
typedef __bf16 bf16x8_t __attribute__((ext_vector_type(8)));
typedef float f32x4 __attribute__((ext_vector_type(4)));

#define GAS __attribute__((address_space(1)))
#define LAS __attribute__((address_space(3)))

// ---------------------------------------------------------------------------
// BFP quant-dequant (group=16 along K, m_bit=8) fp32 -> bf16 (values exact).
// Near-roofline (~70 us for 432 MiB) -- unchanged.
// ---------------------------------------------------------------------------
__global__ __launch_bounds__(256) void bfp_quant_f32_to_bf16(
    const float* __restrict__ x, bf16* __restrict__ y, long long n4) {
  long long t = (long long)blockIdx.x * 256 + threadIdx.x;
  if (t >= n4) return;
  const float4 v = reinterpret_cast<const float4*>(x)[t];

  float a = fmaxf(fmaxf(fabsf(v.x), fabsf(v.y)), fmaxf(fabsf(v.z), fabsf(v.w)));
  a = fmaxf(a, __shfl_xor(a, 1));
  a = fmaxf(a, __shfl_xor(a, 2));   // group max over 4 lanes = 16 elems

  float q0, q1, q2, q3;
  if (a > 0.0f) {
    int ex = (int)((__float_as_uint(a) >> 23) & 0xffu) - 127;
    float scale = ldexpf(1.0f, ex - 7);   // 2^(ex-7)
    float inv   = ldexpf(1.0f, 7 - ex);   // exact power of 2: x*inv == x/scale
    q0 = fminf(fmaxf(rintf(v.x * inv), -127.0f), 127.0f) * scale;
    q1 = fminf(fmaxf(rintf(v.y * inv), -127.0f), 127.0f) * scale;
    q2 = fminf(fmaxf(rintf(v.z * inv), -127.0f), 127.0f) * scale;
    q3 = fminf(fmaxf(rintf(v.w * inv), -127.0f), 127.0f) * scale;
  } else {
    q0 = q1 = q2 = q3 = 0.0f;
  }
  bf16x4_t o = { (__bf16)q0, (__bf16)q1, (__bf16)q2, (__bf16)q3 };
  reinterpret_cast<bf16x4_t*>(y)[t] = o;
}

// ---------------------------------------------------------------------------
// GEMM: C[M,N] = A[M,K] * B[N,K]^T + bias[N], bf16 in / fp32 out.
// 256x256 tile, BK=64, 512 threads (8 waves 2Mx4N), 128 KiB dbuf LDS,
// st_16x32 swizzle (bank-conflict-free, PMC-verified 0).
//
// ROUND-5 CHANGE: single-barrier phases (8 -> 4 barriers per K-tile).
// The pre-MFMA barrier protected nothing (hazard ledger below references
// only phase-ENDING barriers); it globally serialized the all-wave read
// window against the all-wave MFMA window. Without it, wave X's ds_reads
// overlap wave Y's MFMA cluster (LDS pipe || matrix pipe, m114), and each
// wave enters its MFMAs as soon as ITS OWN reads land (lgkmcnt(0)).
// Phase = { ds_reads; stage-issue; lgkmcnt(0); setprio(1); 16 MFMA;
//           setprio(0); [vmcnt(6) at p4]; s_barrier }.
// Skew is bounded to one phase by the ending barrier.
//
// Staging (depth 3 half-tiles, counted vmcnt(6), round-4 ledger, verified):
//   p1: stage B(t+1).h1 -> Bsn    p3: stage A(t+2).h0+h1 -> Asc
//   p4: stage B(t+2).h0 -> Bsc;  vmcnt(6) drains exactly tile t+1's 8 loads
//   (in-flight at p4's wait: 14 = [A(t+1)4, B(t+1)h0 2, B(t+1)h1 2,
//    A(t+2)4, B(t+2)h0 2]; leave 6 = A(t+2)+B(t+2)h0).
// Overwrite-hazard ledger (ending barriers only):
//   p3's A(t+2)->Asc: a0/a1 readers drained by their own lgkm0 before
//     p1/p2 MFMAs; p3 stage issues after p2's ENDING barrier.  OK
//   p4's B(t+2).h0->Bsc (+ next-p1's h1): b0/b1 readers drained before
//     p1/p3 MFMAs; stages issue after p3's/p4's ENDING barriers.  OK
//   Tile t+1 reads gated by p4's vmcnt(6) + ENDING barrier.          OK
// ---------------------------------------------------------------------------
#define BM 256
#define BN 256
#define BK 64
#define THREADS 512

#define BAR() do {                                          \
    asm volatile("" ::: "memory");                          \
    __builtin_amdgcn_s_barrier();                           \
    asm volatile("" ::: "memory");                          \
  } while (0)

template <int H>
__device__ __forceinline__ void stage_half(const char* gb, char* ldsb,
                                           const int goff[4], long long kb,
                                           int tid) {
#pragma unroll
  for (int i = 2 * H; i < 2 * H + 2; ++i) {
    __builtin_amdgcn_global_load_lds(
        (const GAS unsigned int*)(gb + (goff[i] + kb)),
        (LAS unsigned int*)(ldsb + tid * 16 + i * 8192), 16, 0, 0);
  }
}

// One K-tile (4 single-barrier phases).
__device__ __forceinline__ void ktile(
    char* const Asc, char* const Bsc, char* const Bsn,
    f32x4 (&acc)[8][4],
    const char* Ab, const char* Bb, const int* goff,
    long long kbB1, long long kbAB2, int tid, int wofs, int wr, int wc) {
  bf16x8_t a0[4][2], a1[4][2], b0[2][2], b1[2][2];

  // ---- p1: read a0(8)+b0(4); stage B(t+1).h1 ---- Q00
#pragma unroll
  for (int m = 0; m < 4; ++m)
#pragma unroll
    for (int ks = 0; ks < 2; ++ks)
      a0[m][ks] = *(const bf16x8_t*)(Asc + ((((wr * 8 + m) * 2 + ks) << 10) + wofs));
#pragma unroll
  for (int n = 0; n < 2; ++n)
#pragma unroll
    for (int ks = 0; ks < 2; ++ks)
      b0[n][ks] = *(const bf16x8_t*)(Bsc + ((((wc * 4 + n) * 2 + ks) << 10) + wofs));
  stage_half<1>(Bb, Bsn, goff, kbB1, tid);
  asm volatile("s_waitcnt lgkmcnt(0)");
  __builtin_amdgcn_s_setprio(1);
#pragma unroll
  for (int m = 0; m < 4; ++m)
#pragma unroll
    for (int n = 0; n < 2; ++n)
#pragma unroll
      for (int ks = 0; ks < 2; ++ks)
        acc[m][n] = __builtin_amdgcn_mfma_f32_16x16x32_bf16(
            a0[m][ks], b0[n][ks], acc[m][n], 0, 0, 0);
  __builtin_amdgcn_s_setprio(0);
  BAR();

  // ---- p2: read a1(8) ---- Q10
#pragma unroll
  for (int m = 0; m < 4; ++m)
#pragma unroll
    for (int ks = 0; ks < 2; ++ks)
      a1[m][ks] = *(const bf16x8_t*)(Asc + ((((wr * 8 + 4 + m) * 2 + ks) << 10) + wofs));
  asm volatile("s_waitcnt lgkmcnt(0)");
  __builtin_amdgcn_s_setprio(1);
#pragma unroll
  for (int m = 0; m < 4; ++m)
#pragma unroll
    for (int n = 0; n < 2; ++n)
#pragma unroll
      for (int ks = 0; ks < 2; ++ks)
        acc[4 + m][n] = __builtin_amdgcn_mfma_f32_16x16x32_bf16(
            a1[m][ks], b0[n][ks], acc[4 + m][n], 0, 0, 0);
  __builtin_amdgcn_s_setprio(0);
  BAR();

  // ---- p3: read b1(4); stage A(t+2).h0+h1 -> Asc ---- Q11
#pragma unroll
  for (int n = 0; n < 2; ++n)
#pragma unroll
    for (int ks = 0; ks < 2; ++ks)
      b1[n][ks] = *(const bf16x8_t*)(Bsc + ((((wc * 4 + 2 + n) * 2 + ks) << 10) + wofs));
  stage_half<0>(Ab, Asc, goff, kbAB2, tid);
  stage_half<1>(Ab, Asc, goff, kbAB2, tid);
  asm volatile("s_waitcnt lgkmcnt(0)");
  __builtin_amdgcn_s_setprio(1);
#pragma unroll
  for (int m = 0; m < 4; ++m)
#pragma unroll
    for (int n = 0; n < 2; ++n)
#pragma unroll
      for (int ks = 0; ks < 2; ++ks)
        acc[4 + m][2 + n] = __builtin_amdgcn_mfma_f32_16x16x32_bf16(
            a1[m][ks], b1[n][ks], acc[4 + m][2 + n], 0, 0, 0);
  __builtin_amdgcn_s_setprio(0);
  BAR();

  // ---- p4: stage B(t+2).h0 -> Bsc; counted vmcnt(6) ---- Q01
  stage_half<0>(Bb, Bsc, goff, kbAB2, tid);
  __builtin_amdgcn_s_setprio(1);
#pragma unroll
  for (int m = 0; m < 4; ++m)
#pragma unroll
    for (int n = 0; n < 2; ++n)
#pragma unroll
      for (int ks = 0; ks < 2; ++ks)
        acc[m][2 + n] = __builtin_amdgcn_mfma_f32_16x16x32_bf16(
            a0[m][ks], b1[n][ks], acc[m][2 + n], 0, 0, 0);
  __builtin_amdgcn_s_setprio(0);
  asm volatile("s_waitcnt vmcnt(6)" ::: "memory");  // tile t+1 landed
  BAR();
}

__global__ __launch_bounds__(THREADS, 2) void gemm_bf16_bt_8ph(
    const bf16* __restrict__ A,   // [Mc,K] row-major (chunk)
    const bf16* __restrict__ B,   // [N,K] row-major (i.e. B^T of the GEMM)
    const float* __restrict__ bias,
    float* __restrict__ C,        // [Mc,N] row-major (chunk)
    int N, int K) {
  extern __shared__ char smem[];  // 131072 B: [buf][A 32K | B 32K]

  const int tid  = threadIdx.x;
  const int wave = tid >> 6;
  const int lane = tid & 63;
  const int wr   = wave >> 2;     // 0..1 -> 128 rows of C
  const int wc   = wave & 3;      // 0..3 -> 64 cols of C
  const int quad = lane >> 4;     // 0..3
  const int ln   = lane & 15;
  const int NT   = K / BK;        // must be even (K=4096 -> 64)

  // T1: bijective XCD swizzle (nwg = 16 * (rows/256), always % 8 == 0).
  const int gx   = gridDim.x;
  const int nwg  = gx * gridDim.y;
  const int orig = blockIdx.y * gx + blockIdx.x;
  const int swz  = (orig & 7) * (nwg >> 3) + (orig >> 3);
  const int bm   = swz / gx;
  const int bn   = swz % gx;

  const long long kstride = (long long)K * 2;
  const char* Ab = (const char*)A + (long long)bm * BM * kstride;
  const char* Bb = (const char*)B + (long long)bn * BN * kstride;

  // Per-lane staging source offsets (inverse-swizzled global source so the
  // linear global_load_lds dest + swizzled ds_read form the identity).
  int goff[4];
#pragma unroll
  for (int i = 0; i < 4; ++i) {
    const int o = tid * 16 + i * 8192;
    const int s = o >> 10;          // subtile 0..31
    int w = o & 1023;
    w ^= ((w >> 9) & 1) << 5;       // st_16x32 swizzle
    const int grow = (s >> 1) * 16 + (w >> 6);
    const int gcb  = (s & 1) * 64 + (w & 63);
    goff[i] = grow * (K * 2) + gcb;
  }
  // Swizzled within-subtile ds_read offset.
  const int wofs = (ln * 64 + quad * 16) ^ ((ln & 8) << 2);

  char* const As0 = smem;
  char* const Bs0 = smem + 32768;
  char* const As1 = smem + 65536;
  char* const Bs1 = smem + 98304;

  f32x4 acc[8][4];
#pragma unroll
  for (int m = 0; m < 8; ++m)
#pragma unroll
    for (int n = 0; n < 4; ++n)
      acc[m][n] = (f32x4){0.0f, 0.0f, 0.0f, 0.0f};

  // Prologue (matches steady-state in-flight ordering):
  //   A(0), B(0) -> buf0; A(1) -> buf1; B(1).h0 -> buf1.   14 loads.
  //   vmcnt(6): tile 0 landed, 3 half-tiles (A(1)+B(1).h0) in flight.
  stage_half<0>(Ab, As0, goff, 0, tid);
  stage_half<1>(Ab, As0, goff, 0, tid);
  stage_half<0>(Bb, Bs0, goff, 0, tid);
  stage_half<1>(Bb, Bs0, goff, 0, tid);
  {
    const long long k1 = (NT > 1) ? (long long)BK * 2 : 0;
    stage_half<0>(Ab, As1, goff, k1, tid);
    stage_half<1>(Ab, As1, goff, k1, tid);
    stage_half<0>(Bb, Bs1, goff, k1, tid);
  }
  asm volatile("s_waitcnt vmcnt(6)" ::: "memory");
  __builtin_amdgcn_s_barrier();
  asm volatile("" ::: "memory");

  for (int t = 0; t < NT; t += 2) {
    const long long kbB1e = (long long)((t + 1 < NT) ? t + 1 : NT - 1) * (BK * 2);
    const long long kbAB2e = (long long)((t + 2 < NT) ? t + 2 : NT - 1) * (BK * 2);
    const long long kbB1o = kbAB2e;
    const long long kbAB2o = (long long)((t + 3 < NT) ? t + 3 : NT - 1) * (BK * 2);
    // even tile t: cur (As0,Bs0); B(t+1).h1 -> Bs1; A/B(t+2) -> As0/Bs0
    ktile(As0, Bs0, Bs1, acc, Ab, Bb, goff, kbB1e, kbAB2e, tid, wofs, wr, wc);
    // odd tile t+1: cur (As1,Bs1); B(t+2).h1 -> Bs0; A/B(t+3) -> As1/Bs1
    ktile(As1, Bs1, Bs0, acc, Ab, Bb, goff, kbB1o, kbAB2o, tid, wofs, wr, wc);
  }
  // Drain clamped tail stages before exit.
  asm volatile("s_waitcnt vmcnt(0) lgkmcnt(0)" ::: "memory");

  // Epilogue: C/D mapping col = lane&15, row = quad*4 + reg (m89-verified).
  const long long row0 = (long long)bm * BM + wr * 128;
  const int col0 = bn * BN + wc * 64;
#pragma unroll
  for (int n = 0; n < 4; ++n) {
    const int col = col0 + n * 16 + ln;
    const float bv = bias[col];
#pragma unroll
    for (int m = 0; m < 8; ++m) {
      const long long row = row0 + m * 16 + quad * 4;
#pragma unroll
      for (int r = 0; r < 4; ++r)
        C[(row + r) * (long long)N + col] = acc[m][n][r] + bv;
    }
  }
}

extern "C" void kernel_launch(void* const* d_in, const int* in_sizes, int n_in,
                              void* d_out, int out_size, void* d_ws, size_t ws_size,
                              hipStream_t stream) {
  const float* inp    = (const float*)d_in[0];  // [B,S,K] fp32
  const float* weight = (const float*)d_in[1];  // [N,K]   fp32
  const float* bias   = (const float*)d_in[2];  // [N]     fp32
  float* out = (float*)d_out;                   // [B,S,N] fp32

  const int N = in_sizes[2];              // 4096
  const int K = in_sizes[1] / N;          // 4096
  const int M = in_sizes[0] / K;          // 16384

  // Workspace layout:
  //   [0, qw_bytes)   : qw [N,K] bf16  (32 MiB)
  //   [qw_bytes, ...) : qx chunk [Mc,K] bf16, Mc multiple of BM (=256)
  const size_t qw_bytes  = (size_t)N * K * sizeof(bf16);
  const size_t row_bytes = (size_t)K * sizeof(bf16);

  long long Mc;
  if (ws_size >= qw_bytes + (size_t)M * row_bytes) {
    Mc = M;  // everything fits: single GEMM over the full problem
  } else if (ws_size >= qw_bytes + (size_t)BM * row_bytes) {
    Mc = (long long)((ws_size - qw_bytes) / row_bytes) / BM * BM;
  } else {
    Mc = BM;  // desperate floor; requires ws_size >= 34 MiB for correctness
  }

  bf16* qw = (bf16*)d_ws;
  bf16* qx = (bf16*)((char*)d_ws + qw_bytes);

  // 128 KiB dynamic LDS opt-in (host-side, graph-capture transparent).
  static bool lds_attr_done = false;
  if (!lds_attr_done) {
    (void)hipFuncSetAttribute((const void*)gemm_bf16_bt_8ph,
                              hipFuncAttributeMaxDynamicSharedMemorySize,
                              131072);
    lds_attr_done = true;
  }

  // Quantize weight once (32 MiB bf16).
  const long long n4w = (long long)N * K / 4;
  hipLaunchKernelGGL(bfp_quant_f32_to_bf16, dim3((unsigned)((n4w + 255) / 256)),
                     dim3(256), 0, stream, weight, qw, n4w);

  // Chunk over M: quantize Mc input rows, GEMM them, repeat. Same stream =>
  // serialized; chunk i+1's quant never overlaps chunk i's GEMM reads.
  for (long long m0 = 0; m0 < M; m0 += Mc) {
    const long long rows = (M - m0 < Mc) ? (M - m0) : Mc;
    const long long n4x  = rows * K / 4;
    hipLaunchKernelGGL(bfp_quant_f32_to_bf16, dim3((unsigned)((n4x + 255) / 256)),
                       dim3(256), 0, stream,
                       inp + m0 * K, qx, n4x);
    hipLaunchKernelGGL(gemm_bf16_bt_8ph,
                       dim3(N / BN, (unsigned)(rows / BM)), dim3(THREADS),
                       131072, stream,
                       qx, qw, bias, out + m0 * N, N, K);
  }
}